// Round 3
// baseline (807.836 us; speedup 1.0000x reference)
//
#include <hip/hip_runtime.h>

#define H 1024
#define W 1024
#define NIMG 8
#define CPT 4                   // columns per thread
#define TH 4                    // output rows per wave-tile (8 blocks/CU)
#define NBX 4                   // x-quadrants: 64 lanes * 4 cols * 4 = 1024
#define WPB 4                   // waves per block, stacked in y
#define NBY (H / (TH * WPB))    // 64
#define NBLK (NBX * NBY * NIMG) // 2048 blocks = 8 blocks/CU = 32 waves/CU
#define NWAVES (NBLK * WPB)     // 8192
#define EPS 1e-5f

// One row's contribution (scaled by `scale`) to the 5 vertical window sums,
// for 4 consecutive output columns [X, X+4).
// Only the center float4 per tensor is loaded at full rate; the 4-left /
// 4-right halo pixels come from neighbor lanes via __shfl (DS pipe) instead
// of duplicate L1 loads. Wave-edge lanes (0, 63) load their halo directly
// (exec-masked, 2 active lanes); halo is zero outside the image.
__device__ __forceinline__ void row_apply(
    const float* __restrict__ Irow, const float* __restrict__ Jrow,
    int X, bool l0, bool l63, bool okL, bool okR, float scale,
    float wI[CPT], float wJ[CPT], float wII[CPT], float wJJ[CPT],
    float wIJ[CPT])
{
  float a[12], b[12];
  { float4 q = *reinterpret_cast<const float4*>(Irow + X);
    a[4]=q.x; a[5]=q.y; a[6]=q.z; a[7]=q.w;
    float4 p = *reinterpret_cast<const float4*>(Jrow + X);
    b[4]=p.x; b[5]=p.y; b[6]=p.z; b[7]=p.w; }

  // edge-lane halo loads (zero-filled when outside the image)
  float4 qE = make_float4(0.f,0.f,0.f,0.f);
  float4 pE = make_float4(0.f,0.f,0.f,0.f);
  if ((l0 && okL) || (l63 && okR)) {
    const int eoff = l0 ? -4 : 4;
    qE = *reinterpret_cast<const float4*>(Irow + X + eoff);
    pE = *reinterpret_cast<const float4*>(Jrow + X + eoff);
  }

  // left halo: lane i-1's center px (lane 0: its own edge load / zero)
  { float t0 = __shfl_up(a[4], 1, 64), t1 = __shfl_up(a[5], 1, 64);
    float t2 = __shfl_up(a[6], 1, 64), t3 = __shfl_up(a[7], 1, 64);
    a[0] = l0 ? qE.x : t0; a[1] = l0 ? qE.y : t1;
    a[2] = l0 ? qE.z : t2; a[3] = l0 ? qE.w : t3; }
  { float t0 = __shfl_up(b[4], 1, 64), t1 = __shfl_up(b[5], 1, 64);
    float t2 = __shfl_up(b[6], 1, 64), t3 = __shfl_up(b[7], 1, 64);
    b[0] = l0 ? pE.x : t0; b[1] = l0 ? pE.y : t1;
    b[2] = l0 ? pE.z : t2; b[3] = l0 ? pE.w : t3; }
  // right halo: lane i+1's center px (lane 63: its own edge load / zero)
  { float t0 = __shfl_down(a[4], 1, 64), t1 = __shfl_down(a[5], 1, 64);
    float t2 = __shfl_down(a[6], 1, 64), t3 = __shfl_down(a[7], 1, 64);
    a[8]  = l63 ? qE.x : t0; a[9]  = l63 ? qE.y : t1;
    a[10] = l63 ? qE.z : t2; a[11] = l63 ? qE.w : t3; }
  { float t0 = __shfl_down(b[4], 1, 64), t1 = __shfl_down(b[5], 1, 64);
    float t2 = __shfl_down(b[6], 1, 64), t3 = __shfl_down(b[7], 1, 64);
    b[8]  = l63 ? pE.x : t0; b[9]  = l63 ? pE.y : t1;
    b[10] = l63 ? pE.z : t2; b[11] = l63 ? pE.w : t3; }

  // horizontal 9-box rowsums, incremental across the 4 cols; window update
  // fused (RS values die immediately -> low register pressure).
  float sI=0.f, sJ=0.f, sII=0.f, sJJ=0.f, sIJ=0.f;
  #pragma unroll
  for (int k = 0; k < 9; ++k) {
    sI += a[k]; sJ += b[k];
    sII = fmaf(a[k], a[k], sII);
    sJJ = fmaf(b[k], b[k], sJJ);
    sIJ = fmaf(a[k], b[k], sIJ);
  }
  wI[0]  = fmaf(scale, sI,  wI[0]);
  wJ[0]  = fmaf(scale, sJ,  wJ[0]);
  wII[0] = fmaf(scale, sII, wII[0]);
  wJJ[0] = fmaf(scale, sJJ, wJJ[0]);
  wIJ[0] = fmaf(scale, sIJ, wIJ[0]);
  #pragma unroll
  for (int i = 1; i < CPT; ++i) {
    float an=a[i+8], al=a[i-1], bn=b[i+8], bl=b[i-1];
    sI += an - al;  sJ += bn - bl;
    sII = fmaf(-al, al, fmaf(an, an, sII));
    sJJ = fmaf(-bl, bl, fmaf(bn, bn, sJJ));
    sIJ = fmaf(-al, bl, fmaf(an, bn, sIJ));
    wI[i]  = fmaf(scale, sI,  wI[i]);
    wJ[i]  = fmaf(scale, sJ,  wJ[i]);
    wII[i] = fmaf(scale, sII, wII[i]);
    wJJ[i] = fmaf(scale, sJJ, wJJ[i]);
    wIJ[i] = fmaf(scale, sIJ, wIJ[i]);
  }
}

// No LDS, no barriers: each wave walks a 256-col x 4-row tile, each thread a
// 4-col strip with vertical running window sums in registers. All applies are
// branchless (clamped row + zero scale) -> one straight-line pipeline.
// Latency hiding: 2048 blocks -> 8 blocks/CU -> up to 8 waves/SIMD.
__global__ __launch_bounds__(256, 6)
void ncc_main(const float* __restrict__ I, const float* __restrict__ J,
              float* __restrict__ partial) {
  const int tid  = threadIdx.x;
  const int lane = tid & 63, wv = tid >> 6;
  // XCD-bijective remap (NBLK = 2048 = 8 * 256): XCD k (= bid % 8) processes
  // contiguous tiles [k*256,(k+1)*256) == exactly image k -> halo re-reads
  // stay inside one XCD's L2.
  const int bid  = (int)blockIdx.x;
  const int tile = ((bid & 7) << 8) | (bid >> 3);
  const int bx   = tile & (NBX - 1);
  const int rest = tile >> 2;             // [0, 512)
  const int by   = rest & (NBY - 1);
  const int bz   = rest >> 6;             // image index
  const int X  = bx * 256 + lane * CPT;
  const int y0 = (by * WPB + wv) * TH;
  const bool l0  = (lane == 0), l63 = (lane == 63);
  const bool okL = (X >= 4);
  const bool okR = (X + 8 <= W);
  const size_t img_off = (size_t)bz * H * W;
  const float* Ip = I + img_off;
  const float* Jp = J + img_off;

  float wI[CPT], wJ[CPT], wII[CPT], wJJ[CPT], wIJ[CPT];
  #pragma unroll
  for (int i = 0; i < CPT; ++i) { wI[i]=wJ[i]=wII[i]=wJJ[i]=wIJ[i]=0.f; }
  float acc = 0.f;
  const float inv81 = 1.0f / 81.0f;

  // sgn=+1: add row r's rowsums; sgn=-1: subtract. Branchless: OOB rows load
  // a clamped (valid, L2-hot) row and contribute with scale 0.
  auto apply = [&](int r, float sgn) {
    const float scale = ((unsigned)r < (unsigned)H) ? sgn : 0.f;
    const int rc = min(max(r, 0), H - 1);
    row_apply(Ip + (size_t)rc * W, Jp + (size_t)rc * W, X,
              l0, l63, okL, okR, scale, wI, wJ, wII, wJJ, wIJ);
  };
  auto emit = [&]() {
    #pragma unroll
    for (int i = 0; i < CPT; ++i) {
      float cross = fmaf(-(wI[i] * wJ[i]), inv81, wIJ[i]);
      float Iv    = fmaf(-(wI[i] * wI[i]), inv81, wII[i]);
      float Jv    = fmaf(-(wJ[i] * wJ[i]), inv81, wJJ[i]);
      acc = fmaf(cross * cross,
                 __builtin_amdgcn_rcpf(fmaf(Iv, Jv, EPS)), acc);
    }
  };

  // build initial window: rows y0-4 .. y0+4
  #pragma unroll
  for (int k = 0; k < 9; ++k) apply(y0 - 4 + k, 1.0f);
  emit();
  // steady state: add r, drop r-9, emit y=r-4
  #pragma unroll
  for (int k = 0; k < TH - 1; ++k) {
    apply(y0 + 5 + k, 1.0f);
    apply(y0 - 4 + k, -1.0f);
    emit();
  }

  // wave reduction -> one partial per wave (no LDS, no barrier)
  #pragma unroll
  for (int off = 32; off > 0; off >>= 1)
    acc += __shfl_down(acc, off, 64);
  if (lane == 0)
    partial[tile * WPB + wv] = acc;
}

__global__ __launch_bounds__(256)
void ncc_reduce(const float* __restrict__ partial, float* __restrict__ out) {
  __shared__ float red[4];
  const int tid = threadIdx.x;
  const float4* p4 = reinterpret_cast<const float4*>(partial);
  float s = 0.f;
  #pragma unroll
  for (int i = tid; i < NWAVES / 4; i += 256) {
    float4 v = p4[i];
    s += (v.x + v.y) + (v.z + v.w);
  }
  #pragma unroll
  for (int off = 32; off > 0; off >>= 1)
    s += __shfl_down(s, off, 64);
  if ((tid & 63) == 0) red[tid >> 6] = s;
  __syncthreads();
  if (tid == 0)
    out[0] = (red[0] + red[1] + red[2] + red[3]) *
             (1.0f / (float)((size_t)NIMG * H * W));
}

extern "C" void kernel_launch(void* const* d_in, const int* in_sizes, int n_in,
                              void* d_out, int out_size, void* d_ws, size_t ws_size,
                              hipStream_t stream) {
  const float* I = (const float*)d_in[0];
  const float* J = (const float*)d_in[1];
  float* out     = (float*)d_out;
  float* partial = (float*)d_ws;            // 8192 * 4 B = 32 KB

  hipLaunchKernelGGL(ncc_main, dim3(NBLK), dim3(256), 0, stream, I, J, partial);
  hipLaunchKernelGGL(ncc_reduce, dim3(1), dim3(256), 0, stream, partial, out);
}

// Round 4
// 111.376 us; speedup vs baseline: 7.2533x; 7.2533x over previous
//
#include <hip/hip_runtime.h>

#define H 1024
#define W 1024
#define NIMG 8
#define CPT 4                   // columns per thread
#define TH 8                    // output rows per wave-tile
#define NBX 4                   // x-quadrants: 64 lanes * 4 cols * 4 = 1024
#define WPB 4                   // waves per block, stacked in y
#define NBY (H / (TH * WPB))    // 32
#define NBLK (NBX * NBY * NIMG) // 1024 blocks = 4 blocks/CU = 16 waves/CU
#define NWAVES (NBLK * WPB)     // 4096
#define EPS 1e-5f

struct RS { float I[CPT], J[CPT], II[CPT], JJ[CPT], IJ[CPT]; };

// Horizontal 9-box rowsums for 4 consecutive output columns [X, X+4).
// Only the center float4 per tensor is loaded at full rate; the 4-left /
// 4-right halo pixels come from neighbor lanes via __shfl (DS pipe) instead
// of duplicate L1 loads (cuts L1 vector-load traffic 3x). Wave-edge lanes
// (0, 63) load their halo directly (exec-masked, 2 active lanes); halo is
// zero outside the image.
__device__ __forceinline__ void row_rs(const float* __restrict__ Irow,
                                       const float* __restrict__ Jrow,
                                       int X, bool l0, bool l63,
                                       bool okL, bool okR, RS& o) {
  float a[12], b[12];
  { float4 q = *reinterpret_cast<const float4*>(Irow + X);
    a[4]=q.x; a[5]=q.y; a[6]=q.z; a[7]=q.w;
    float4 p = *reinterpret_cast<const float4*>(Jrow + X);
    b[4]=p.x; b[5]=p.y; b[6]=p.z; b[7]=p.w; }

  // edge-lane halo loads (zero when outside the image)
  float4 qE = make_float4(0.f,0.f,0.f,0.f);
  float4 pE = make_float4(0.f,0.f,0.f,0.f);
  if ((l0 && okL) || (l63 && okR)) {
    const int eoff = l0 ? -4 : 4;
    qE = *reinterpret_cast<const float4*>(Irow + X + eoff);
    pE = *reinterpret_cast<const float4*>(Jrow + X + eoff);
  }

  // left halo = lane i-1's center px (lane 0: its own edge load / zero)
  { float t0 = __shfl_up(a[4], 1, 64), t1 = __shfl_up(a[5], 1, 64);
    float t2 = __shfl_up(a[6], 1, 64), t3 = __shfl_up(a[7], 1, 64);
    a[0] = l0 ? qE.x : t0; a[1] = l0 ? qE.y : t1;
    a[2] = l0 ? qE.z : t2; a[3] = l0 ? qE.w : t3; }
  { float t0 = __shfl_up(b[4], 1, 64), t1 = __shfl_up(b[5], 1, 64);
    float t2 = __shfl_up(b[6], 1, 64), t3 = __shfl_up(b[7], 1, 64);
    b[0] = l0 ? pE.x : t0; b[1] = l0 ? pE.y : t1;
    b[2] = l0 ? pE.z : t2; b[3] = l0 ? pE.w : t3; }
  // right halo = lane i+1's center px (lane 63: its own edge load / zero)
  { float t0 = __shfl_down(a[4], 1, 64), t1 = __shfl_down(a[5], 1, 64);
    float t2 = __shfl_down(a[6], 1, 64), t3 = __shfl_down(a[7], 1, 64);
    a[8]  = l63 ? qE.x : t0; a[9]  = l63 ? qE.y : t1;
    a[10] = l63 ? qE.z : t2; a[11] = l63 ? qE.w : t3; }
  { float t0 = __shfl_down(b[4], 1, 64), t1 = __shfl_down(b[5], 1, 64);
    float t2 = __shfl_down(b[6], 1, 64), t3 = __shfl_down(b[7], 1, 64);
    b[8]  = l63 ? pE.x : t0; b[9]  = l63 ? pE.y : t1;
    b[10] = l63 ? pE.z : t2; b[11] = l63 ? pE.w : t3; }

  float sI=0.f, sJ=0.f, sII=0.f, sJJ=0.f, sIJ=0.f;
  #pragma unroll
  for (int k = 0; k < 9; ++k) {
    sI += a[k]; sJ += b[k];
    sII = fmaf(a[k], a[k], sII);
    sJJ = fmaf(b[k], b[k], sJJ);
    sIJ = fmaf(a[k], b[k], sIJ);
  }
  o.I[0]=sI; o.J[0]=sJ; o.II[0]=sII; o.JJ[0]=sJJ; o.IJ[0]=sIJ;
  #pragma unroll
  for (int i = 1; i < CPT; ++i) {
    float an=a[i+8], al=a[i-1], bn=b[i+8], bl=b[i-1];
    sI += an - al;  sJ += bn - bl;
    sII = fmaf(-al, al, fmaf(an, an, sII));
    sJJ = fmaf(-bl, bl, fmaf(bn, bn, sJJ));
    sIJ = fmaf(-al, bl, fmaf(an, bn, sIJ));
    o.I[i]=sI; o.J[i]=sJ; o.II[i]=sII; o.JJ[i]=sJJ; o.IJ[i]=sIJ;
  }
}

// No LDS, no barriers: each wave independently walks a 256-col x 8-row tile,
// each thread a 4-col strip with vertical running window sums in registers.
// Leaving rows are re-loaded (L1/L2-hot) and recomputed instead of ring-kept.
// Latency hiding from TLP: 1024 blocks -> 4 blocks/CU -> 4 waves/SIMD.
// NOTE: __launch_bounds__(256,4) only — a tighter cap (256,6) forced VGPR=40
// and spilled the a[]/b[] arrays to scratch (1.4 GB WRITE_SIZE, 7x slower).
__global__ __launch_bounds__(256, 4)
void ncc_main(const float* __restrict__ I, const float* __restrict__ J,
              float* __restrict__ partial) {
  const int tid  = threadIdx.x;
  const int lane = tid & 63, wv = tid >> 6;
  // XCD-bijective remap (NBLK = 1024 = 8 * 128): XCD k (= bid % 8) processes
  // contiguous tiles [k*128, (k+1)*128) == exactly image k -> vertical-halo
  // re-reads stay inside one XCD's L2 instead of cross-XCD HBM re-fetches.
  const int bid  = (int)blockIdx.x;
  const int tile = ((bid & 7) << 7) | (bid >> 3);
  const int bx   = tile & (NBX - 1);
  const int rest = tile / NBX;            // [0, 256)
  const int by   = rest & (NBY - 1);
  const int bz   = rest / NBY;            // image index
  const int X  = bx * 256 + lane * CPT;
  const int y0 = (by * WPB + wv) * TH;
  const bool l0  = (lane == 0), l63 = (lane == 63);
  const bool okL = (X >= 4);
  const bool okR = (X + 8 <= W);
  const size_t img_off = (size_t)bz * H * W;
  const float* Ip = I + img_off;
  const float* Jp = J + img_off;

  float wI[CPT], wJ[CPT], wII[CPT], wJJ[CPT], wIJ[CPT];
  #pragma unroll
  for (int i = 0; i < CPT; ++i) { wI[i]=wJ[i]=wII[i]=wJJ[i]=wIJ[i]=0.f; }
  float acc = 0.f;
  const float inv81 = 1.0f / 81.0f;

  // sgn=+1: add row r's rowsums into window; sgn=-1: subtract (leave)
  auto apply = [&](int r, float sgn) {
    if ((unsigned)r < (unsigned)H) {      // wave-uniform row guard
      RS o;
      row_rs(Ip + (size_t)r * W, Jp + (size_t)r * W, X,
             l0, l63, okL, okR, o);
      #pragma unroll
      for (int i = 0; i < CPT; ++i) {
        wI[i]  = fmaf(sgn, o.I[i],  wI[i]);
        wJ[i]  = fmaf(sgn, o.J[i],  wJ[i]);
        wII[i] = fmaf(sgn, o.II[i], wII[i]);
        wJJ[i] = fmaf(sgn, o.JJ[i], wJJ[i]);
        wIJ[i] = fmaf(sgn, o.IJ[i], wIJ[i]);
      }
    }
  };
  auto emit = [&]() {
    #pragma unroll
    for (int i = 0; i < CPT; ++i) {
      float cross = fmaf(-(wI[i] * wJ[i]), inv81, wIJ[i]);
      float Iv    = fmaf(-(wI[i] * wI[i]), inv81, wII[i]);
      float Jv    = fmaf(-(wJ[i] * wJ[i]), inv81, wJJ[i]);
      acc = fmaf(cross * cross,
                 __builtin_amdgcn_rcpf(fmaf(Iv, Jv, EPS)), acc);
    }
  };

  // warm-up: rows y0-4 .. y0+3
  for (int k = 0; k < 8; ++k) apply(y0 - 4 + k, 1.0f);
  // first output row: add y0+4, window = rows y0-4..y0+4
  apply(y0 + 4, 1.0f);
  emit();
  // steady state: add r, drop r-9, emit y=r-4
  for (int k = 0; k < TH - 1; ++k) {
    apply(y0 + 5 + k, 1.0f);
    apply(y0 - 4 + k, -1.0f);
    emit();
  }

  // wave reduction -> one partial per wave (no LDS, no barrier)
  #pragma unroll
  for (int off = 32; off > 0; off >>= 1)
    acc += __shfl_down(acc, off, 64);
  if (lane == 0)
    partial[tile * WPB + wv] = acc;
}

__global__ __launch_bounds__(256)
void ncc_reduce(const float* __restrict__ partial, float* __restrict__ out) {
  __shared__ float red[4];
  const int tid = threadIdx.x;
  const float4* p4 = reinterpret_cast<const float4*>(partial);
  float s = 0.f;
  #pragma unroll
  for (int i = tid; i < NWAVES / 4; i += 256) {
    float4 v = p4[i];
    s += (v.x + v.y) + (v.z + v.w);
  }
  #pragma unroll
  for (int off = 32; off > 0; off >>= 1)
    s += __shfl_down(s, off, 64);
  if ((tid & 63) == 0) red[tid >> 6] = s;
  __syncthreads();
  if (tid == 0)
    out[0] = (red[0] + red[1] + red[2] + red[3]) *
             (1.0f / (float)((size_t)NIMG * H * W));
}

extern "C" void kernel_launch(void* const* d_in, const int* in_sizes, int n_in,
                              void* d_out, int out_size, void* d_ws, size_t ws_size,
                              hipStream_t stream) {
  const float* I = (const float*)d_in[0];
  const float* J = (const float*)d_in[1];
  float* out     = (float*)d_out;
  float* partial = (float*)d_ws;            // 4096 * 4 B = 16 KB

  hipLaunchKernelGGL(ncc_main, dim3(NBLK), dim3(256), 0, stream, I, J, partial);
  hipLaunchKernelGGL(ncc_reduce, dim3(1), dim3(256), 0, stream, partial, out);
}